// Round 1
// baseline (98.098 us; speedup 1.0000x reference)
//
#include <hip/hip_runtime.h>
#include <hip/hip_bf16.h>
#include <math.h>

typedef __bf16 bf16_t;
typedef __bf16 bf16x8 __attribute__((ext_vector_type(8)));
typedef float f32x4 __attribute__((ext_vector_type(4)));

#define N2 4096
#define NHALF 2048
#define DIM 512
#define TEMP_INV 2.0f   // 1/TEMPERATURE

// ---------------------------------------------------------------------------
// Kernel 1: row-normalize fp32 -> bf16. One wave (64 lanes) per row; 8 floats
// per lane via two float4 loads; butterfly reduce sum-of-squares.
// ---------------------------------------------------------------------------
__global__ __launch_bounds__(256) void k_normalize(const float* __restrict__ x,
                                                   bf16_t* __restrict__ xn) {
    const int row  = (blockIdx.x * blockDim.x + threadIdx.x) >> 6;
    const int lane = threadIdx.x & 63;
    const float4* xr = reinterpret_cast<const float4*>(x + (size_t)row * DIM);
    float4 a = xr[lane * 2];
    float4 b = xr[lane * 2 + 1];
    float ss = a.x*a.x + a.y*a.y + a.z*a.z + a.w*a.w
             + b.x*b.x + b.y*b.y + b.z*b.z + b.w*b.w;
#pragma unroll
    for (int off = 32; off; off >>= 1) ss += __shfl_xor(ss, off, 64);
    const float scale = 1.0f / fmaxf(sqrtf(ss), 1e-8f);
    float v[8] = {a.x, a.y, a.z, a.w, b.x, b.y, b.z, b.w};
    bf16x8 o;
#pragma unroll
    for (int t = 0; t < 8; ++t) o[t] = (bf16_t)(v[t] * scale);
    *reinterpret_cast<bf16x8*>(xn + (size_t)row * DIM + lane * 8) = o;
}

// ---------------------------------------------------------------------------
// Kernel 2: pos_i = 2*dot(xn_i, xn_{(i+N)%2N}), diag_i = 2*dot(xn_i, xn_i).
// One wave per row.
// ---------------------------------------------------------------------------
__global__ __launch_bounds__(256) void k_posdiag(const bf16_t* __restrict__ xn,
                                                 float* __restrict__ pos,
                                                 float* __restrict__ diag) {
    const int row  = (blockIdx.x * blockDim.x + threadIdx.x) >> 6;
    const int lane = threadIdx.x & 63;
    const int prow = (row + NHALF) & (N2 - 1);
    bf16x8 vi = *reinterpret_cast<const bf16x8*>(xn + (size_t)row  * DIM + lane * 8);
    bf16x8 vj = *reinterpret_cast<const bf16x8*>(xn + (size_t)prow * DIM + lane * 8);
    float dii = 0.0f, dij = 0.0f;
#pragma unroll
    for (int t = 0; t < 8; ++t) {
        float fi = (float)vi[t], fj = (float)vj[t];
        dii += fi * fi;
        dij += fi * fj;
    }
#pragma unroll
    for (int off = 32; off; off >>= 1) {
        dii += __shfl_xor(dii, off, 64);
        dij += __shfl_xor(dij, off, 64);
    }
    if (lane == 0) {
        pos[row]  = TEMP_INV * dij;
        diag[row] = TEMP_INV * dii;
    }
}

// ---------------------------------------------------------------------------
// Kernel 3: sim-GEMM with exp+rowsum epilogue. C = Xn * Xn^T (both operands
// K-contiguous). 128x128 tile per 256-thread block (4 waves, 2x2 of 64x64),
// BK=32, mfma_f32_16x16x32_bf16, global_load_lds width-16 staging.
// Never materializes sim: epilogue computes exp(2*c) and row-sums.
// ---------------------------------------------------------------------------
__device__ __forceinline__ void load_lds16(const bf16_t* g, bf16_t* l) {
    __builtin_amdgcn_global_load_lds(
        (const __attribute__((address_space(1))) unsigned int*)g,
        (__attribute__((address_space(3))) unsigned int*)l,
        16, 0, 0);
}

__global__ __launch_bounds__(256) void k_simgemm(const bf16_t* __restrict__ xn,
                                                 float* __restrict__ rowsum) {
    // LDS tiles: [128 rows][32 k] bf16, row-major, no padding (required by
    // global_load_lds wave-uniform-base + lane*16 dest rule).
    __shared__ bf16_t As[128 * 32];
    __shared__ bf16_t Bs[128 * 32];
    __shared__ float  rpart[128];

    const int tid  = threadIdx.x;
    const int lane = tid & 63;
    const int wid  = tid >> 6;
    const int wr   = wid >> 1;   // wave row half (0..1)
    const int wc   = wid & 1;    // wave col half (0..1)
    const int q    = lane >> 4;  // quad 0..3
    const int l15  = lane & 15;
    const int bm   = blockIdx.x;
    const int bn   = blockIdx.y;

    if (tid < 128) rpart[tid] = 0.0f;

    // staging: thread loads 16B (8 bf16). flat elem idx = tid*8 ->
    // row = tid/4 (0..63), col = (tid%4)*8. Second issue covers rows 64..127.
    const int sRow = tid >> 2;
    const int sCol = (tid & 3) * 8;
    const bf16_t* gA0 = xn + (size_t)(bm * 128 + sRow) * DIM + sCol;
    const bf16_t* gB0 = xn + (size_t)(bn * 128 + sRow) * DIM + sCol;
    bf16_t* lA0 = &As[tid * 8];
    bf16_t* lA1 = &As[2048 + tid * 8];
    bf16_t* lB0 = &Bs[tid * 8];
    bf16_t* lB1 = &Bs[2048 + tid * 8];

    f32x4 acc[4][4] = {};

    for (int k0 = 0; k0 < DIM; k0 += 32) {
        __syncthreads();  // previous iteration's LDS reads complete
        load_lds16(gA0 + k0, lA0);
        load_lds16(gA0 + (size_t)64 * DIM + k0, lA1);
        load_lds16(gB0 + k0, lB0);
        load_lds16(gB0 + (size_t)64 * DIM + k0, lB1);
        __syncthreads();  // drains vmcnt -> LDS tiles visible

        bf16x8 af[4], bf[4];
#pragma unroll
        for (int mt = 0; mt < 4; ++mt)
            af[mt] = *reinterpret_cast<const bf16x8*>(
                &As[(wr * 64 + mt * 16 + l15) * 32 + q * 8]);
#pragma unroll
        for (int nt = 0; nt < 4; ++nt)
            bf[nt] = *reinterpret_cast<const bf16x8*>(
                &Bs[(wc * 64 + nt * 16 + l15) * 32 + q * 8]);
#pragma unroll
        for (int mt = 0; mt < 4; ++mt)
#pragma unroll
            for (int nt = 0; nt < 4; ++nt)
                acc[mt][nt] = __builtin_amdgcn_mfma_f32_16x16x32_bf16(
                    af[mt], bf[nt], acc[mt][nt], 0, 0, 0);
    }

    // Epilogue: C/D layout col=lane&15, row=q*4+r. exp(2*c), sum over this
    // block's 128 columns per row, then one global atomic per row.
#pragma unroll
    for (int mt = 0; mt < 4; ++mt) {
#pragma unroll
        for (int r = 0; r < 4; ++r) {
            float p = 0.0f;
#pragma unroll
            for (int nt = 0; nt < 4; ++nt)
                p += __expf(TEMP_INV * acc[mt][nt][r]);
            p += __shfl_xor(p, 1, 64);
            p += __shfl_xor(p, 2, 64);
            p += __shfl_xor(p, 4, 64);
            p += __shfl_xor(p, 8, 64);
            if (l15 == 0)
                atomicAdd(&rpart[wr * 64 + mt * 16 + q * 4 + r], p);
        }
    }
    __syncthreads();
    if (tid < 128) atomicAdd(&rowsum[bm * 128 + tid], rpart[tid]);
}

// ---------------------------------------------------------------------------
// Kernel 4: loss = mean_i( log(S_i - exp(diag_i)) - pos_i )
// ---------------------------------------------------------------------------
__global__ __launch_bounds__(256) void k_finalize(const float* __restrict__ rowsum,
                                                  const float* __restrict__ pos,
                                                  const float* __restrict__ diag,
                                                  float* __restrict__ out) {
    __shared__ float red[256];
    float s = 0.0f;
    for (int i = threadIdx.x; i < N2; i += 256)
        s += __logf(rowsum[i] - __expf(diag[i])) - pos[i];
    red[threadIdx.x] = s;
    __syncthreads();
    for (int st = 128; st; st >>= 1) {
        if (threadIdx.x < st) red[threadIdx.x] += red[threadIdx.x + st];
        __syncthreads();
    }
    if (threadIdx.x == 0) out[0] = red[0] / (float)N2;
}

// ---------------------------------------------------------------------------
extern "C" void kernel_launch(void* const* d_in, const int* in_sizes, int n_in,
                              void* d_out, int out_size, void* d_ws, size_t ws_size,
                              hipStream_t stream) {
    (void)in_sizes; (void)n_in; (void)out_size; (void)ws_size;
    const float* x = (const float*)d_in[0];
    float* out = (float*)d_out;

    char* ws = (char*)d_ws;
    bf16_t* xn     = (bf16_t*)ws;                          // 4096*512*2 = 4 MB
    float*  rowsum = (float*)(ws + (size_t)N2 * DIM * 2);  // 16 KB
    float*  pos    = rowsum + N2;                          // 16 KB
    float*  diag   = pos + N2;                             // 16 KB

    hipMemsetAsync(rowsum, 0, N2 * sizeof(float), stream);
    k_normalize<<<N2 / 4, 256, 0, stream>>>(x, xn);
    k_posdiag<<<N2 / 4, 256, 0, stream>>>(xn, pos, diag);
    dim3 grid(32, 32);
    k_simgemm<<<grid, 256, 0, stream>>>(xn, rowsum);
    k_finalize<<<1, 256, 0, stream>>>(rowsum, pos, diag, out);
}

// Round 2
// 82.422 us; speedup vs baseline: 1.1902x; 1.1902x over previous
//
#include <hip/hip_runtime.h>
#include <hip/hip_bf16.h>
#include <math.h>

typedef __bf16 bf16_t;
typedef __bf16 bf16x8 __attribute__((ext_vector_type(8)));
typedef float f32x4 __attribute__((ext_vector_type(4)));

#define N2 4096
#define NHALF 2048
#define DIM 512
#define TEMP_INV 2.0f   // 1/TEMPERATURE

// ---------------------------------------------------------------------------
// Kernel 1 (fused prep): one wave per row-PAIR (i, i+N). Loads both fp32 rows,
// computes norms + cross-dot, writes both bf16 rows, pos[i]=pos[p] (symmetric),
// diag per row from the bf16-rounded values (matches what the GEMM will sum),
// and zeroes this block's slice of rowsum.
// ---------------------------------------------------------------------------
__global__ __launch_bounds__(256) void k_prep(const float* __restrict__ x,
                                              bf16_t* __restrict__ xn,
                                              float* __restrict__ pos,
                                              float* __restrict__ diag,
                                              float* __restrict__ rowsum) {
    const int pair = blockIdx.x * 4 + (threadIdx.x >> 6);   // 0..2047
    const int lane = threadIdx.x & 63;
    const int rowi = pair;
    const int rowp = pair + NHALF;

    const float4* xi = reinterpret_cast<const float4*>(x + (size_t)rowi * DIM);
    const float4* xp = reinterpret_cast<const float4*>(x + (size_t)rowp * DIM);
    float4 a0 = xi[lane * 2], a1 = xi[lane * 2 + 1];
    float4 b0 = xp[lane * 2], b1 = xp[lane * 2 + 1];

    float ssi = a0.x*a0.x + a0.y*a0.y + a0.z*a0.z + a0.w*a0.w
              + a1.x*a1.x + a1.y*a1.y + a1.z*a1.z + a1.w*a1.w;
    float ssp = b0.x*b0.x + b0.y*b0.y + b0.z*b0.z + b0.w*b0.w
              + b1.x*b1.x + b1.y*b1.y + b1.z*b1.z + b1.w*b1.w;
    float dot = a0.x*b0.x + a0.y*b0.y + a0.z*b0.z + a0.w*b0.w
              + a1.x*b1.x + a1.y*b1.y + a1.z*b1.z + a1.w*b1.w;
#pragma unroll
    for (int off = 32; off; off >>= 1) {
        ssi += __shfl_xor(ssi, off, 64);
        ssp += __shfl_xor(ssp, off, 64);
        dot += __shfl_xor(dot, off, 64);
    }
    const float ni = fmaxf(sqrtf(ssi), 1e-8f);
    const float np = fmaxf(sqrtf(ssp), 1e-8f);
    const float sci = 1.0f / ni, scp = 1.0f / np;

    float va[8] = {a0.x, a0.y, a0.z, a0.w, a1.x, a1.y, a1.z, a1.w};
    float vb[8] = {b0.x, b0.y, b0.z, b0.w, b1.x, b1.y, b1.z, b1.w};
    bf16x8 oi, op;
    float dii = 0.0f, dpp = 0.0f;
#pragma unroll
    for (int t = 0; t < 8; ++t) {
        oi[t] = (bf16_t)(va[t] * sci);
        op[t] = (bf16_t)(vb[t] * scp);
        float fi = (float)oi[t], fp_ = (float)op[t];
        dii += fi * fi;
        dpp += fp_ * fp_;
    }
    *reinterpret_cast<bf16x8*>(xn + (size_t)rowi * DIM + lane * 8) = oi;
    *reinterpret_cast<bf16x8*>(xn + (size_t)rowp * DIM + lane * 8) = op;
#pragma unroll
    for (int off = 32; off; off >>= 1) {
        dii += __shfl_xor(dii, off, 64);
        dpp += __shfl_xor(dpp, off, 64);
    }
    if (lane == 0) {
        const float pv = TEMP_INV * dot * sci * scp;
        pos[rowi] = pv;
        pos[rowp] = pv;          // sim is symmetric: pos[i] == pos[i+N]
        diag[rowi] = TEMP_INV * dii;
        diag[rowp] = TEMP_INV * dpp;
    }
    // zero rowsum (8 entries per block covers 4096 over 512 blocks)
    if (threadIdx.x < 8) rowsum[blockIdx.x * 8 + threadIdx.x] = 0.0f;
}

// ---------------------------------------------------------------------------
// Kernel 2: symmetric sim-GEMM, upper-triangle blocks only (528 of 1024).
// Off-diagonal blocks contribute exp-tile row sums to bm-rows AND column sums
// to bn-rows. 128x128 tile, 4 waves 2x2, BK=32, mfma 16x16x32 bf16,
// global_load_lds width-16 staging.
// ---------------------------------------------------------------------------
__device__ __forceinline__ void load_lds16(const bf16_t* g, bf16_t* l) {
    __builtin_amdgcn_global_load_lds(
        (const __attribute__((address_space(1))) unsigned int*)g,
        (__attribute__((address_space(3))) unsigned int*)l,
        16, 0, 0);
}

__global__ __launch_bounds__(256) void k_simgemm(const bf16_t* __restrict__ xn,
                                                 float* __restrict__ rowsum) {
    __shared__ bf16_t As[128 * 32];
    __shared__ bf16_t Bs[128 * 32];
    __shared__ float  rpA[128];
    __shared__ float  rpB[128];

    // unrank blockIdx.x -> (bm <= bn) upper-triangle pair
    const int t = blockIdx.x;
    int bn = (int)((sqrtf(8.0f * (float)t + 1.0f) - 1.0f) * 0.5f);
    while ((bn * (bn + 1)) / 2 > t) --bn;
    while (((bn + 1) * (bn + 2)) / 2 <= t) ++bn;
    const int bm = t - (bn * (bn + 1)) / 2;
    const bool diagb = (bm == bn);

    const int tid  = threadIdx.x;
    const int lane = tid & 63;
    const int wid  = tid >> 6;
    const int wr   = wid >> 1;
    const int wc   = wid & 1;
    const int q    = lane >> 4;
    const int l15  = lane & 15;

    if (tid < 128) { rpA[tid] = 0.0f; rpB[tid] = 0.0f; }

    const int sRow = tid >> 2;
    const int sCol = (tid & 3) * 8;
    const bf16_t* gA0 = xn + (size_t)(bm * 128 + sRow) * DIM + sCol;
    const bf16_t* gB0 = xn + (size_t)(bn * 128 + sRow) * DIM + sCol;
    bf16_t* lA0 = &As[tid * 8];
    bf16_t* lA1 = &As[2048 + tid * 8];
    bf16_t* lB0 = &Bs[tid * 8];
    bf16_t* lB1 = &Bs[2048 + tid * 8];

    f32x4 acc[4][4] = {};

    for (int k0 = 0; k0 < DIM; k0 += 32) {
        __syncthreads();
        load_lds16(gA0 + k0, lA0);
        load_lds16(gA0 + (size_t)64 * DIM + k0, lA1);
        load_lds16(gB0 + k0, lB0);
        load_lds16(gB0 + (size_t)64 * DIM + k0, lB1);
        __syncthreads();

        bf16x8 af[4], bf[4];
#pragma unroll
        for (int mt = 0; mt < 4; ++mt)
            af[mt] = *reinterpret_cast<const bf16x8*>(
                &As[(wr * 64 + mt * 16 + l15) * 32 + q * 8]);
#pragma unroll
        for (int nt = 0; nt < 4; ++nt)
            bf[nt] = *reinterpret_cast<const bf16x8*>(
                &Bs[(wc * 64 + nt * 16 + l15) * 32 + q * 8]);
#pragma unroll
        for (int mt = 0; mt < 4; ++mt)
#pragma unroll
            for (int nt = 0; nt < 4; ++nt)
                acc[mt][nt] = __builtin_amdgcn_mfma_f32_16x16x32_bf16(
                    af[mt], bf[nt], acc[mt][nt], 0, 0, 0);
    }

    // Epilogue. C/D: row = wr*64+mt*16+q*4+r, col = wc*64+nt*16+l15.
    float colacc[4] = {0.0f, 0.0f, 0.0f, 0.0f};
#pragma unroll
    for (int mt = 0; mt < 4; ++mt) {
        float rowp[4] = {0.0f, 0.0f, 0.0f, 0.0f};
#pragma unroll
        for (int nt = 0; nt < 4; ++nt)
#pragma unroll
            for (int r = 0; r < 4; ++r) {
                float e = __expf(TEMP_INV * acc[mt][nt][r]);
                rowp[r] += e;
                colacc[nt] += e;
            }
#pragma unroll
        for (int r = 0; r < 4; ++r) {
            float p = rowp[r];
            p += __shfl_xor(p, 1, 64);
            p += __shfl_xor(p, 2, 64);
            p += __shfl_xor(p, 4, 64);
            p += __shfl_xor(p, 8, 64);
            if (l15 == 0) atomicAdd(&rpA[wr * 64 + mt * 16 + q * 4 + r], p);
        }
    }
    if (!diagb) {
#pragma unroll
        for (int nt = 0; nt < 4; ++nt) {
            float c = colacc[nt];
            c += __shfl_xor(c, 16, 64);
            c += __shfl_xor(c, 32, 64);
            if (q == 0) atomicAdd(&rpB[wc * 64 + nt * 16 + l15], c);
        }
    }
    __syncthreads();
    if (tid < 128) {
        atomicAdd(&rowsum[bm * 128 + tid], rpA[tid]);
    } else if (!diagb) {
        atomicAdd(&rowsum[bn * 128 + (tid - 128)], rpB[tid - 128]);
    }
}

// ---------------------------------------------------------------------------
// Kernel 3: loss = mean_i( log(S_i - exp(diag_i)) - pos_i )
// ---------------------------------------------------------------------------
__global__ __launch_bounds__(256) void k_finalize(const float* __restrict__ rowsum,
                                                  const float* __restrict__ pos,
                                                  const float* __restrict__ diag,
                                                  float* __restrict__ out) {
    __shared__ float red[256];
    float s = 0.0f;
    for (int i = threadIdx.x; i < N2; i += 256)
        s += __logf(rowsum[i] - __expf(diag[i])) - pos[i];
    red[threadIdx.x] = s;
    __syncthreads();
    for (int st = 128; st; st >>= 1) {
        if (threadIdx.x < st) red[threadIdx.x] += red[threadIdx.x + st];
        __syncthreads();
    }
    if (threadIdx.x == 0) out[0] = red[0] / (float)N2;
}

// ---------------------------------------------------------------------------
extern "C" void kernel_launch(void* const* d_in, const int* in_sizes, int n_in,
                              void* d_out, int out_size, void* d_ws, size_t ws_size,
                              hipStream_t stream) {
    (void)in_sizes; (void)n_in; (void)out_size; (void)ws_size;
    const float* x = (const float*)d_in[0];
    float* out = (float*)d_out;

    char* ws = (char*)d_ws;
    bf16_t* xn     = (bf16_t*)ws;                          // 4 MB
    float*  rowsum = (float*)(ws + (size_t)N2 * DIM * 2);  // 16 KB
    float*  pos    = rowsum + N2;
    float*  diag   = pos + N2;

    k_prep<<<512, 256, 0, stream>>>(x, xn, pos, diag, rowsum);
    k_simgemm<<<528, 256, 0, stream>>>(xn, rowsum);
    k_finalize<<<1, 256, 0, stream>>>(rowsum, pos, diag, out);
}